// Round 9
// baseline (131.945 us; speedup 1.0000x reference)
//
#include <hip/hip_runtime.h>
#include <math.h>

#define CEPS 1e-9f

typedef _Float16 half8 __attribute__((ext_vector_type(8)));
typedef float floatx4 __attribute__((ext_vector_type(4)));

// x  : [4,56,56,8,32] fp32    W: [4,4,128,32] fp32    bias: [128] fp32
// out: [4,112,112,128] fp32 act
//
// votes[b'][pix][m=(pix,i)][ca] = sum_{tap,ci} xf[...]*W[kh][kw][ca][ci]
// xf[b'][h][w][i][ci] = x[i&3][h][w][2b'+(i>>2)][ci]   (reference reshape scramble)
//
// R9: mfma_f32_16x16x32_f16. Wave = M16 (2 pixels along v x 8 i), N=128
// (8 tiles of 16), K=128 (4 taps = 4 chunks of K=32). acc = 8x4 = 32 VGPRs
// (vs 64 for the 32x32 shape) -> fits __launch_bounds__(256,4) WITHOUT the
// spill that killed R6 (R6 peak live ~150 vs cap 128 -> 400 MB scratch).
// Block = 4 waves = 4u x 2v pixel tile, one parity (rh,rw), one b'.
// A-frag: m = l&15 = pix*8+i, k-quarter q = l>>4 (ci = q*8..+7).
// C/D:    col = l&15 = n(ca-within-tile), row m = (l>>4)*4+reg -> lane's
//         pix = l>>5, i = ((l>>4)&1)*4 + reg.
// W staged by prep_w as f16 B-fragments in d_ws, 32 KB/parity (R7 measured:
// inline fp32 W fetch+convert costs ~45 us of L2-latency stall vs the table).
// Routing (R7/R8 structure): per-pixel LDS transpose (wave-local, no barrier)
// to lane=(c,i), a(16) in-register; i-sums pure DPP; fast rcp/rsq.
// scx row stride 9: stride-8 aliased all cI rows (8-way conflicts, R6).

template<int CTRL>
__device__ __forceinline__ float dpp_add(float v) {
    return v + __int_as_float(__builtin_amdgcn_update_dpp(
        0, __float_as_int(v), CTRL, 0xF, 0xF, false));
}

// sum over the 8-lane group (lane bits 0..2), result in all 8 lanes — pure VALU
__device__ __forceinline__ float sum_i8(float v) {
    v = dpp_add<0xB1>(v);    // quad_perm [1,0,3,2] == xor1
    v = dpp_add<0x4E>(v);    // quad_perm [2,3,0,1] == xor2
    v = dpp_add<0x141>(v);   // row_half_mirror: cross-quad (valid after quad sums)
    return v;
}

__device__ __forceinline__ float4 sel4(bool c, float4 a, float4 b) {
    return make_float4(c ? a.x : b.x, c ? a.y : b.y, c ? a.z : b.z, c ? a.w : b.w);
}

// B[k][n] table: idx = ((parity*4 + s)*8 + t)*64 + l -> 8 f16
// n = t*16 + (l&15), k = s*32 + (l>>4)*8 + j  (tap = s, ci = (l>>4)*8 + j)
__global__ __launch_bounds__(256) void prep_w(const float* __restrict__ Wt,
                                              _Float16* __restrict__ wb) {
    int idx = blockIdx.x * 256 + threadIdx.x;    // [0, 8192)
    int parity = idx >> 11;
    int s = (idx >> 9) & 3;
    int t = (idx >> 6) & 7;
    int l = idx & 63;
    int rh = parity >> 1, rw = parity & 1;
    int n = t * 16 + (l & 15);
    int ci0 = (l >> 4) << 3;
    int kh = ((s >> 1) << 1) + 1 - rh;
    int kw = ((s & 1) << 1) + 1 - rw;
    const float* src = Wt + (((kh * 4 + kw) * 128 + n) << 5) + ci0;
    float4 w0 = *(const float4*)src;
    float4 w1 = *(const float4*)(src + 4);
    half8 hv;
    hv[0] = (_Float16)w0.x; hv[1] = (_Float16)w0.y;
    hv[2] = (_Float16)w0.z; hv[3] = (_Float16)w0.w;
    hv[4] = (_Float16)w1.x; hv[5] = (_Float16)w1.y;
    hv[6] = (_Float16)w1.z; hv[7] = (_Float16)w1.w;
    *(half8*)(wb + ((long)idx << 3)) = hv;
}

__global__ __launch_bounds__(256, 4) void caps_mfma(
    const float* __restrict__ x,
    const _Float16* __restrict__ wb,
    const float* __restrict__ bias,
    float* __restrict__ out)
{
    // x tile: [cell(5u x 3v)][i(8)][ci padded 32->40] f16
    __shared__ _Float16 xt[15 * 8 * 40];       // 9600 B
    // per-wave vote-transpose scratch: [ca(128)][i(8) padded ->9] fp32
    __shared__ float scx[4][1152];             // 18432 B

    const int tid = threadIdx.x;
    const int tile = blockIdx.x;            // 0..391 : 14 u-tiles x 28 v-tiles
    const int tu = tile / 28, tv = tile - tu * 28;
    const int u0 = tu * 4, v0 = tv * 2;
    const int rh = blockIdx.y >> 1;         // p & 1
    const int rw = blockIdx.y & 1;          // q & 1
    const int bp = blockIdx.z;              // b'
    const _Float16* wsrc = wb + ((long)blockIdx.y << 14);   // parity slice, 32 KB

    // ---- stage x: fp32 -> f16 tile [ri(5)][rj(3)][i(8)][ci], zero-filled OOB ----
    #pragma unroll
    for (int it = 0; it < 2; ++it) {
        int idx = tid + (it << 8);
        if (idx < 480) {
            int cell = idx >> 5;            // 0..14
            int r = idx & 31;
            int i = r >> 2;
            int ci0 = (r & 3) << 3;
            int ri = cell / 3, rj = cell - ri * 3;
            int gi = u0 + rh - 1 + ri;
            int gj = v0 + rw - 1 + rj;
            float tmp[8] = {0.f, 0.f, 0.f, 0.f, 0.f, 0.f, 0.f, 0.f};
            if ((unsigned)gi < 56u && (unsigned)gj < 56u) {
                const float* src = x + (((i & 3) * 56 + gi) * 56 + gj) * 256
                                     + ((bp * 2 + (i >> 2)) << 5) + ci0;
                float4 a0 = *(const float4*)src;
                float4 a1 = *(const float4*)(src + 4);
                tmp[0] = a0.x; tmp[1] = a0.y; tmp[2] = a0.z; tmp[3] = a0.w;
                tmp[4] = a1.x; tmp[5] = a1.y; tmp[6] = a1.z; tmp[7] = a1.w;
            }
            half8 hv;
            #pragma unroll
            for (int j = 0; j < 8; ++j) hv[j] = (_Float16)tmp[j];
            *(half8*)(xt + (cell * 8 + i) * 40 + ci0) = hv;
        }
    }
    __syncthreads();

    const int l = tid & 63;
    const int w = tid >> 6;                 // wave = u-row within tile
    const int q = l >> 4;                   // k-quarter
    const int pixA = (l & 15) >> 3;         // A-side pixel (v within pair)
    const int iA = l & 7;

    floatx4 acc[8];
    #pragma unroll
    for (int t = 0; t < 8; ++t)
        #pragma unroll
        for (int j = 0; j < 4; ++j) acc[t][j] = 0.f;

    // ---- MFMA K-loop: 4 taps (K=32 each) x 8 n-tiles; B from L1-resident table ----
    #pragma unroll
    for (int s = 0; s < 4; ++s) {
        const int tkh = s >> 1, tkw = s & 1;
        const int ucell = w + 1 - tkh;
        const int vcell = pixA + 1 - tkw;
        half8 af = *(const half8*)(xt + ((ucell * 3 + vcell) * 8 + iA) * 40 + (q << 3));
        #pragma unroll
        for (int t = 0; t < 8; ++t) {
            half8 bf = *(const half8*)(wsrc + (((s * 8 + t) * 64 + l) << 3));
            acc[t] = __builtin_amdgcn_mfma_f32_16x16x32_f16(af, bf, acc[t], 0, 0, 0);
        }
    }

    // ---- routing: lane = (c = l>>3, i = l&7), a(16) in-register ----
    float* scb = &scx[w][0];                // wave-local, no barrier needed
    const int cI = l >> 3;
    const int iI = l & 7;
    const int myPix = l >> 5;               // pixel owned by this lane's D rows
    const int iRow = ((l >> 4) & 1) << 2;   // i-base of this lane's D rows

    float4 bq[4];                           // bias[c*16 + a]
    #pragma unroll
    for (int t = 0; t < 4; ++t) bq[t] = *(const float4*)(bias + cI * 16 + t * 4);

    #pragma unroll
    for (int pixl = 0; pixl < 2; ++pixl) {
        // transpose this pixel's votes: D-layout -> [ca][i] (row stride 9);
        // only the half-wave owning this pixel writes (exec-masked)
        if (myPix == pixl) {
            #pragma unroll
            for (int t = 0; t < 8; ++t)
                #pragma unroll
                for (int reg = 0; reg < 4; ++reg)
                    scb[(t * 16 + (l & 15)) * 9 + iRow + reg] = acc[t][reg];
        }
        float va[16];
        #pragma unroll
        for (int a = 0; a < 16; ++a) va[a] = scb[(cI * 16 + a) * 9 + iI];

        float pre[16], lg = 0.f;

        // ---- round 0: route = 1/8 ----
        #pragma unroll
        for (int a = 0; a < 16; ++a) {
            float s = sum_i8(va[a]);
            pre[a] = fmaf(0.125f, s, (&bq[a >> 2].x)[a & 3]);
        }
        {
            float nq = pre[0] * pre[0];
            #pragma unroll
            for (int a = 1; a < 16; ++a) nq = fmaf(pre[a], pre[a], nq);
            float sc = nq * __builtin_amdgcn_rcpf(1.f + nq)
                          * __builtin_amdgcn_rsqf(nq + CEPS);
            #pragma unroll
            for (int a = 0; a < 16; ++a) pre[a] *= sc;   // pre = act now
            float d = va[0] * pre[0];
            #pragma unroll
            for (int a = 1; a < 16; ++a) d = fmaf(va[a], pre[a], d);
            lg = d;                                       // per-(i,c), no shuffle
        }

        // ---- rounds 1,2 ----
        #pragma unroll
        for (int r = 1; r < 3; ++r) {
            // softmax over c (lane bits 3..5); logits bounded, no max-sub
            float e = __expf(lg);
            float ss = dpp_add<0x128>(e);                 // ror8 == xor8
            ss += __shfl_xor(ss, 16);
            ss += __shfl_xor(ss, 32);
            float route = e * __builtin_amdgcn_rcpf(ss);
            #pragma unroll
            for (int a = 0; a < 16; ++a) {
                float m = sum_i8(route * va[a]);
                pre[a] = m + (&bq[a >> 2].x)[a & 3];
            }
            float nq = pre[0] * pre[0];
            #pragma unroll
            for (int a = 1; a < 16; ++a) nq = fmaf(pre[a], pre[a], nq);
            float sc = nq * __builtin_amdgcn_rcpf(1.f + nq)
                          * __builtin_amdgcn_rsqf(nq + CEPS);
            #pragma unroll
            for (int a = 0; a < 16; ++a) pre[a] *= sc;    // act
            if (r < 2) {
                float d = va[0] * pre[0];
                #pragma unroll
                for (int a = 1; a < 16; ++a) d = fmaf(va[a], pre[a], d);
                lg += d;
            }
        }

        // ---- store: lanes i<4 each write one float4 quad -> fully coalesced ----
        float4 q0 = make_float4(pre[0],  pre[1],  pre[2],  pre[3]);
        float4 q1 = make_float4(pre[4],  pre[5],  pre[6],  pre[7]);
        float4 q2 = make_float4(pre[8],  pre[9],  pre[10], pre[11]);
        float4 q3 = make_float4(pre[12], pre[13], pre[14], pre[15]);
        float4 t0 = sel4((iI & 1) != 0, q1, q0);
        float4 t1 = sel4((iI & 1) != 0, q3, q2);
        float4 o4 = sel4((iI & 2) != 0, t1, t0);
        if (iI < 4) {
            const int p = ((u0 + w) << 1) + rh;
            const int qq = ((v0 + pixl) << 1) + rw;
            *(float4*)(out + (((bp * 112 + p) * 112 + qq) << 7) + cI * 16 + iI * 4) = o4;
        }
    }
}

extern "C" void kernel_launch(void* const* d_in, const int* in_sizes, int n_in,
                              void* d_out, int out_size, void* d_ws, size_t ws_size,
                              hipStream_t stream) {
    const float* x  = (const float*)d_in[0];
    const float* Wt = (const float*)d_in[1];
    const float* b  = (const float*)d_in[2];
    float* out = (float*)d_out;
    _Float16* wb = (_Float16*)d_ws;          // 4 parities x 16384 f16 = 128 KB

    prep_w<<<32, 256, 0, stream>>>(Wt, wb);
    dim3 grid(392, 4, 4);    // 14x28 tiles of 4u x 2v pixels, 4 parities, 4 b'
    caps_mfma<<<grid, 256, 0, stream>>>(x, wb, b, out);
}

// Round 10
// 128.130 us; speedup vs baseline: 1.0298x; 1.0298x over previous
//
#include <hip/hip_runtime.h>
#include <math.h>

#define CEPS 1e-9f

typedef _Float16 half8 __attribute__((ext_vector_type(8)));
typedef float floatx16 __attribute__((ext_vector_type(16)));

// x  : [4,56,56,8,32] fp32    W: [4,4,128,32] fp32    bias: [128] fp32
// out: [4,112,112,128] fp32 act
//
// votes[b'][pix][m=(pixl,i)][ca] = sum_{tap,ci} xf[...]*W[kh][kw][ca][ci]
// xf[b'][h][w][i][ci] = x[i&3][h][w][2b'+(i>>2)][ci]   (reference reshape scramble)
// Wave = M32 (4 pixels along v x 8 i), N=128 (4 tiles), K=128 (8 steps of 16).
// Block = 4 waves = 4x4 pixel tile, one parity (rh,rw), one b'.
// W staged by prep_w as f16 B-fragments in d_ws (16 KB/parity -> L1-resident;
// R7: inline fp32 W fetch+convert cost ~45 us of L2-latency stall vs table).
// Routing: per-pixel LDS transpose (wave-local, no barrier) to lane=(c,i),
// a(16) in-register; i-sums pure DPP; fast rcp/rsq.
//
// REGISTER HISTORY: (256,6)->2.1GB spill (R3); (256,4) with bias+va+pre+acc
// all live -> 400MB spill (R6); (256,3) fits but only 3 blocks/CU (R8, 67us).
// R10: bias moved to LDS (re-read per pixl AFTER the pixel's acc slice dies)
// -> peak live ~110 < 128 -> (256,4) without spill. 16x16 MFMA variant (R9)
// was worse: doubled grid doubled staging overhead, masked writes doubled
// LDS conflicts.
// scx row stride 9: stride-8 aliased all cI rows (8-way conflict, R6).

template<int CTRL>
__device__ __forceinline__ float dpp_add(float v) {
    return v + __int_as_float(__builtin_amdgcn_update_dpp(
        0, __float_as_int(v), CTRL, 0xF, 0xF, false));
}

// sum over the 8-lane group (lane bits 0..2), result in all 8 lanes — pure VALU
__device__ __forceinline__ float sum_i8(float v) {
    v = dpp_add<0xB1>(v);    // quad_perm [1,0,3,2] == xor1
    v = dpp_add<0x4E>(v);    // quad_perm [2,3,0,1] == xor2
    v = dpp_add<0x141>(v);   // row_half_mirror: cross-quad (valid after quad sums)
    return v;
}

__device__ __forceinline__ float4 sel4(bool c, float4 a, float4 b) {
    return make_float4(c ? a.x : b.x, c ? a.y : b.y, c ? a.z : b.z, c ? a.w : b.w);
}

// B[k][n] fragment table: idx = ((parity*8 + s)*4 + t)*64 + l -> 8 f16
__global__ __launch_bounds__(256) void prep_w(const float* __restrict__ Wt,
                                              _Float16* __restrict__ wb) {
    int idx = blockIdx.x * 256 + threadIdx.x;    // [0, 8192)
    int parity = idx >> 11;
    int s = (idx >> 8) & 7;
    int t = (idx >> 6) & 3;
    int l = idx & 63;
    int rh = parity >> 1, rw = parity & 1;
    int n = t * 32 + (l & 31);
    int h = l >> 5;
    int ci0 = ((s & 1) << 4) + (h << 3);
    int kh = ((s >> 2) << 1) + 1 - rh;
    int kw = (((s >> 1) & 1) << 1) + 1 - rw;
    const float* src = Wt + (((kh * 4 + kw) * 128 + n) << 5) + ci0;
    float4 w0 = *(const float4*)src;
    float4 w1 = *(const float4*)(src + 4);
    half8 hv;
    hv[0] = (_Float16)w0.x; hv[1] = (_Float16)w0.y;
    hv[2] = (_Float16)w0.z; hv[3] = (_Float16)w0.w;
    hv[4] = (_Float16)w1.x; hv[5] = (_Float16)w1.y;
    hv[6] = (_Float16)w1.z; hv[7] = (_Float16)w1.w;
    *(half8*)(wb + ((long)idx << 3)) = hv;
}

__global__ __launch_bounds__(256, 4) void caps_mfma(
    const float* __restrict__ x,
    const _Float16* __restrict__ wb,
    const float* __restrict__ bias,
    float* __restrict__ out)
{
    // x tile: [cell(5x5)][i(8)][ci padded 32->40] f16
    __shared__ _Float16 xt[25 * 8 * 40];       // 16000 B
    // per-wave vote-transpose scratch: [ca(128)][i(8) padded ->9] fp32
    __shared__ float scx[4][1152];             // 18432 B
    // bias staged [c][a padded 16->17]: b128 reads broadcast, banks spread
    __shared__ float bsh[136];                 // 544 B

    const int tid = threadIdx.x;
    const int tile = blockIdx.x;            // 0..195 : 14x14 tiles of 4x4 pixels
    const int tu = tile / 14, tv = tile - tu * 14;
    const int u0 = tu * 4, v0 = tv * 4;
    const int rh = blockIdx.y >> 1;         // p & 1
    const int rw = blockIdx.y & 1;          // q & 1
    const int bp = blockIdx.z;              // b'
    const _Float16* wsrc = wb + ((long)blockIdx.y << 14);   // parity slice, 16 KB

    if (tid < 128) bsh[(tid >> 4) * 17 + (tid & 15)] = bias[tid];

    // ---- stage x: fp32 -> f16 tile [ri(5)][rj(5)][i(8)][ci], zero-filled OOB ----
    #pragma unroll
    for (int it = 0; it < 4; ++it) {
        int idx = tid + (it << 8);
        if (idx < 800) {
            int cell = idx >> 5;            // 0..24
            int r = idx & 31;
            int i = r >> 2;
            int ci0 = (r & 3) << 3;
            int ri = cell / 5, rj = cell - ri * 5;
            int gi = u0 + rh - 1 + ri;
            int gj = v0 + rw - 1 + rj;
            float tmp[8] = {0.f, 0.f, 0.f, 0.f, 0.f, 0.f, 0.f, 0.f};
            if ((unsigned)gi < 56u && (unsigned)gj < 56u) {
                const float* src = x + (((i & 3) * 56 + gi) * 56 + gj) * 256
                                     + ((bp * 2 + (i >> 2)) << 5) + ci0;
                float4 a0 = *(const float4*)src;
                float4 a1 = *(const float4*)(src + 4);
                tmp[0] = a0.x; tmp[1] = a0.y; tmp[2] = a0.z; tmp[3] = a0.w;
                tmp[4] = a1.x; tmp[5] = a1.y; tmp[6] = a1.z; tmp[7] = a1.w;
            }
            half8 hv;
            #pragma unroll
            for (int j = 0; j < 8; ++j) hv[j] = (_Float16)tmp[j];
            *(half8*)(xt + (cell * 8 + i) * 40 + ci0) = hv;
        }
    }
    __syncthreads();

    const int l = tid & 63;
    const int w = tid >> 6;                 // wave = u-row within tile
    const int col = l & 31, h = l >> 5;
    const int invA = (l & 31) * 40 + (h << 3);

    floatx16 acc[4];
    #pragma unroll
    for (int t = 0; t < 4; ++t)
        #pragma unroll
        for (int j = 0; j < 16; ++j) acc[t][j] = 0.f;

    // ---- MFMA K-loop: 8 k-steps x 4 n-tiles; B-frags from L1-resident table ----
    #pragma unroll
    for (int s = 0; s < 8; ++s) {
        const int tkh = s >> 2;
        const int tkw = (s >> 1) & 1;
        const int row = w + 1 - tkh;
        const int aoff = (row * 5 + 1 - tkw) * 320 + ((s & 1) << 4) + invA;
        half8 af = *(const half8*)(xt + aoff);
        #pragma unroll
        for (int t = 0; t < 4; ++t) {
            half8 bf = *(const half8*)(wsrc + (((s * 4 + t) * 64 + l) << 3));
            acc[t] = __builtin_amdgcn_mfma_f32_32x32x16_f16(af, bf, acc[t], 0, 0, 0);
        }
    }

    // ---- routing: lane = (c = l>>3, i = l&7), a(16) in-register ----
    float* scb = &scx[w][0];                // wave-local, no barrier needed
    const int cI = l >> 3;
    const int iI = l & 7;

    #pragma unroll
    for (int pixl = 0; pixl < 4; ++pixl) {
        // transpose this pixel's votes: C-layout -> [ca][i] (row stride 9)
        #pragma unroll
        for (int t = 0; t < 4; ++t)
            #pragma unroll
            for (int il = 0; il < 4; ++il)
                scb[(t * 32 + col) * 9 + (h << 2) + il] = acc[t][pixl * 4 + il];
        float va[16];
        #pragma unroll
        for (int a = 0; a < 16; ++a) va[a] = scb[(cI * 16 + a) * 9 + iI];
        // bias loaded per-pixl (after this pixel's acc slice dies) -> peak regs
        // stay under the (256,4) cap of 128; broadcast ds_read_b128
        float4 bq[4];
        #pragma unroll
        for (int t = 0; t < 4; ++t) bq[t] = *(const float4*)(bsh + cI * 17 + t * 4);

        float pre[16], lg = 0.f;

        // ---- round 0: route = 1/8 ----
        #pragma unroll
        for (int a = 0; a < 16; ++a) {
            float s = sum_i8(va[a]);
            pre[a] = fmaf(0.125f, s, (&bq[a >> 2].x)[a & 3]);
        }
        {
            float nq = pre[0] * pre[0];
            #pragma unroll
            for (int a = 1; a < 16; ++a) nq = fmaf(pre[a], pre[a], nq);
            float sc = nq * __builtin_amdgcn_rcpf(1.f + nq)
                          * __builtin_amdgcn_rsqf(nq + CEPS);
            #pragma unroll
            for (int a = 0; a < 16; ++a) pre[a] *= sc;   // pre = act now
            float d = va[0] * pre[0];
            #pragma unroll
            for (int a = 1; a < 16; ++a) d = fmaf(va[a], pre[a], d);
            lg = d;                                       // per-(i,c), no shuffle
        }

        // ---- rounds 1,2 ----
        #pragma unroll
        for (int r = 1; r < 3; ++r) {
            // softmax over c (lane bits 3..5); logits bounded, no max-sub
            float e = __expf(lg);
            float ss = dpp_add<0x128>(e);                 // ror8 == xor8
            ss += __shfl_xor(ss, 16);
            ss += __shfl_xor(ss, 32);
            float route = e * __builtin_amdgcn_rcpf(ss);
            #pragma unroll
            for (int a = 0; a < 16; ++a) {
                float m = sum_i8(route * va[a]);
                pre[a] = m + (&bq[a >> 2].x)[a & 3];
            }
            float nq = pre[0] * pre[0];
            #pragma unroll
            for (int a = 1; a < 16; ++a) nq = fmaf(pre[a], pre[a], nq);
            float sc = nq * __builtin_amdgcn_rcpf(1.f + nq)
                          * __builtin_amdgcn_rsqf(nq + CEPS);
            #pragma unroll
            for (int a = 0; a < 16; ++a) pre[a] *= sc;    // act
            if (r < 2) {
                float d = va[0] * pre[0];
                #pragma unroll
                for (int a = 1; a < 16; ++a) d = fmaf(va[a], pre[a], d);
                lg += d;
            }
        }

        // ---- store: lanes i<4 each write one float4 quad -> fully coalesced ----
        float4 q0 = make_float4(pre[0],  pre[1],  pre[2],  pre[3]);
        float4 q1 = make_float4(pre[4],  pre[5],  pre[6],  pre[7]);
        float4 q2 = make_float4(pre[8],  pre[9],  pre[10], pre[11]);
        float4 q3 = make_float4(pre[12], pre[13], pre[14], pre[15]);
        float4 t0 = sel4((iI & 1) != 0, q1, q0);
        float4 t1 = sel4((iI & 1) != 0, q3, q2);
        float4 o4 = sel4((iI & 2) != 0, t1, t0);
        if (iI < 4) {
            const int p = ((u0 + w) << 1) + rh;
            const int q = ((v0 + pixl) << 1) + rw;
            *(float4*)(out + (((bp * 112 + p) * 112 + q) << 7) + cI * 16 + iI * 4) = o4;
        }
    }
}

extern "C" void kernel_launch(void* const* d_in, const int* in_sizes, int n_in,
                              void* d_out, int out_size, void* d_ws, size_t ws_size,
                              hipStream_t stream) {
    const float* x  = (const float*)d_in[0];
    const float* Wt = (const float*)d_in[1];
    const float* b  = (const float*)d_in[2];
    float* out = (float*)d_out;
    _Float16* wb = (_Float16*)d_ws;          // 4 parities x 16384 f16 = 64 KB

    prep_w<<<32, 256, 0, stream>>>(Wt, wb);
    dim3 grid(196, 4, 4);    // 14x14 4x4-pixel tiles, 4 parity classes, 4 b'
    caps_mfma<<<grid, 256, 0, stream>>>(x, wb, b, out);
}